// Round 7
// baseline (46.284 us; speedup 1.0000x reference)
//
#include <hip/hip_runtime.h>
#include <cstdint>
#include <cstddef>

#define TINV 5.0f
#define C5L2E 7.2134752044448170f   // 5 * log2(e)
#define NROWS 4096
#define DDIM 256
#define MM 8192

typedef __bf16 bf16x8 __attribute__((ext_vector_type(8)));
typedef int i32x4 __attribute__((ext_vector_type(4)));
typedef float f32x4 __attribute__((ext_vector_type(4)));

typedef const void __attribute__((address_space(1)))* gas_ptr;
typedef void __attribute__((address_space(3)))* las_ptr;

// ------- normalize rows of [Z1;Z2] -> unit L2, store bf16; zero rowsumAcc -------
__global__ __launch_bounds__(256, 2)
void nrm_kernel(const float* __restrict__ Z1, const float* __restrict__ Z2,
                unsigned short* __restrict__ Zb, float* __restrict__ rowsumAcc) {
    if (blockIdx.x < 32) rowsumAcc[blockIdx.x * 256 + threadIdx.x] = 0.f;
    const int w = threadIdx.x >> 6, lane = threadIdx.x & 63;
    const int row = blockIdx.x * 4 + w;
    const float* src = row < NROWS ? Z1 + (size_t)row * DDIM
                                   : Z2 + (size_t)(row - NROWS) * DDIM;
    float4 v = reinterpret_cast<const float4*>(src)[lane];
    float ss = v.x*v.x + v.y*v.y + v.z*v.z + v.w*v.w;
    #pragma unroll
    for (int m = 1; m < 64; m <<= 1) ss += __shfl_xor(ss, m, 64);
    float inv = 1.0f / fmaxf(sqrtf(ss), 1e-12f);
    float o[4] = { v.x*inv, v.y*inv, v.z*inv, v.w*inv };
    unsigned short us[4];
    #pragma unroll
    for (int e = 0; e < 4; ++e) {           // RNE f32->bf16 (finite inputs)
        unsigned int b = __builtin_bit_cast(unsigned int, o[e]);
        b += 0x7FFFu + ((b >> 16) & 1u);
        us[e] = (unsigned short)(b >> 16);
    }
    reinterpret_cast<ushort4*>(Zb + (size_t)row * DDIM)[lane] =
        *reinterpret_cast<ushort4*>(us);
}

// ---- stage 64 rows x 512B (32KB) into LDS with 512 threads; source pre-swizzled ----
// read side uses phys_inrow = inrow ^ ((row&15)<<4)
__device__ __forceinline__ void stage32(const unsigned short* Zb, char* ldsdst,
                                        int rowStart, int tid) {
    const char* base = reinterpret_cast<const char*>(Zb) + (size_t)rowStart * 512;
    #pragma unroll
    for (int it = 0; it < 4; ++it) {
        int L = it * 8192 + tid * 16;     // linear LDS byte offset, lane-contiguous
        int row = L >> 9;                 // 0..63
        int soff = row * 512 + ((L & 511) ^ ((row & 15) << 4));
        __builtin_amdgcn_global_load_lds((gas_ptr)(base + soff), (las_ptr)(ldsdst + L),
                                         16, 0, 0);
    }
}

// -------- symmetric fused sim + exp-rowsum/colsum + pos extraction --------
// 32 bands x 256 rows. 8 waves = 4 row-groups(64 rows, A in AGPR) x 2 col-halves(32).
// Block (r,s): d-offsets per split; d=0 diag(rowsum,skip i==j), d=1..15 rowsum+colsum
// (colsum = transpose tile's rowsums, via symmetry), d=16 rowsum-only both endpoints
// (pos column i^4096 lives here). B subtiles (64 cols x 256K = 32KB) double-buffered.
__global__ __launch_bounds__(512, 2)
void sim_lse_kernel(const unsigned short* __restrict__ Zb,
                    float* __restrict__ rowsumAcc,  // [MM], atomic accum
                    float* __restrict__ posArr) {   // [MM]
    __shared__ char lds[65536];                     // 2 x 32KB B buffers
    __shared__ float colRed[4][64];
    const int tid = threadIdx.x;
    const int lane = tid & 63;
    const int w = tid >> 6;
    const int wr = w >> 1, wc = w & 1;              // row-group 0..3, col-half 0..1
    const int r15 = lane & 15, hi = lane >> 4;
    const int r = blockIdx.x >> 3;                  // band 0..31
    const int s = blockIdx.x & 7;                   // split 0..7
    const int R0 = r * 256;
    const int nt = (s < 4) ? 9 : 8;

    // subtile t -> column start (row units of Zb)
    auto colOf = [&](int t) -> int {
        int d, q;
        if (t == 8)        { d = 16;                  q = s; }
        else if (s == 7)   { if (t < 4) { d = 8; q = t; } else { d = 0; q = t - 4; } }
        else               { d = (t < 4) ? s + 1 : s + 9; q = t & 3; }
        return ((r + d) & 31) * 256 + q * 64;
    };

    stage32(Zb, lds, colOf(0), tid);                // subtile 0 -> buf0

    // ---- A fragments: 64 rows x K=256 straight from global into AGPRs ----
    i32x4 qf[4][8];
    {
        const char* abase = reinterpret_cast<const char*>(Zb)
                          + (size_t)(R0 + wr * 64 + r15) * 512 + hi * 16;
        #pragma unroll
        for (int mf = 0; mf < 4; ++mf)
            #pragma unroll
            for (int kk = 0; kk < 8; ++kk)
                qf[mf][kk] = *reinterpret_cast<const i32x4*>(abase + mf * 8192 + kk * 64);
    }

    // thread-constant swizzled B-frag offsets (row&15 == r15 always)
    int baddr0[8];
    #pragma unroll
    for (int kk = 0; kk < 8; ++kk)
        baddr0[kk] = (wc * 32 + r15) * 512 + (((hi << 4) | (kk << 6)) ^ (r15 << 4));

    float rowsum[4][4] = {{0,0,0,0},{0,0,0,0},{0,0,0,0},{0,0,0,0}};
    const int iBase = R0 + wr * 64 + (hi << 2);     // C/D: row=(lane>>4)*4+rr

    for (int t = 0; t < nt; ++t) {
        const int C0 = colOf(t);
        const int cur = (t & 1) << 15;
        if (t < nt - 1) {
            stage32(Zb, lds + (cur ^ 32768), colOf(t + 1), tid);
            asm volatile("s_waitcnt vmcnt(4)" ::: "memory");   // cur's 4 loads done
        } else {
            asm volatile("s_waitcnt vmcnt(0)" ::: "memory");
        }
        __builtin_amdgcn_s_barrier();
        __builtin_amdgcn_sched_barrier(0);

        const int mode = (t == 8) ? 2 : ((s == 7 && t >= 4) ? 1 : 0); // 0 norm,1 diag,2 pos
        #pragma unroll
        for (int nf = 0; nf < 2; ++nf) {
            f32x4 acc[4] = {{0,0,0,0},{0,0,0,0},{0,0,0,0},{0,0,0,0}};
            #pragma unroll
            for (int kk = 0; kk < 8; ++kk) {
                i32x4 b = *reinterpret_cast<const i32x4*>(lds + cur + nf * 8192 + baddr0[kk]);
                #pragma unroll
                for (int mf = 0; mf < 4; ++mf)
                    asm("v_mfma_f32_16x16x32_bf16 %0, %1, %2, %0"
                        : "+v"(acc[mf]) : "a"(qf[mf][kk]), "v"(b));
            }
            const int j = C0 + wc * 32 + nf * 16 + r15;   // C/D: col=lane&15
            if (mode == 0) {
                float s8 = 0.f;
                #pragma unroll
                for (int mf = 0; mf < 4; ++mf)
                    #pragma unroll
                    for (int rr = 0; rr < 4; ++rr) {
                        float e = __builtin_amdgcn_exp2f(fmaf(acc[mf][rr], C5L2E, -C5L2E));
                        rowsum[mf][rr] += e;
                        s8 += e;
                    }
                s8 += __shfl_xor(s8, 16, 64);       // sum the 4 hi-groups (64 rows)
                s8 += __shfl_xor(s8, 32, 64);
                if (hi == 0) colRed[wr][wc * 32 + nf * 16 + r15] = s8;
            } else if (mode == 1) {
                #pragma unroll
                for (int mf = 0; mf < 4; ++mf)
                    #pragma unroll
                    for (int rr = 0; rr < 4; ++rr) {
                        const int i = iBase + mf * 16 + rr;
                        if (j != i)
                            rowsum[mf][rr] += __builtin_amdgcn_exp2f(fmaf(acc[mf][rr], C5L2E, -C5L2E));
                    }
            } else {
                #pragma unroll
                for (int mf = 0; mf < 4; ++mf)
                    #pragma unroll
                    for (int rr = 0; rr < 4; ++rr) {
                        const int i = iBase + mf * 16 + rr;
                        rowsum[mf][rr] += __builtin_amdgcn_exp2f(fmaf(acc[mf][rr], C5L2E, -C5L2E));
                        if (j == (i ^ 4096)) posArr[i] = acc[mf][rr] * TINV;  // unique writer
                    }
            }
        }
        asm volatile("s_waitcnt lgkmcnt(0)" ::: "memory");  // colRed writes visible
        __builtin_amdgcn_sched_barrier(0);
        __builtin_amdgcn_s_barrier();               // done reading cur before overwrite

        // flush colsums of this subtile to partner band rows (symmetry)
        if (mode == 0 && tid < 64) {
            float v = colRed[0][tid] + colRed[1][tid] + colRed[2][tid] + colRed[3][tid];
            atomicAdd(&rowsumAcc[C0 + tid], v);
        }
    }

    // reduce rowsums across the 16 lanes sharing each row, flush atomically
    #pragma unroll
    for (int mf = 0; mf < 4; ++mf)
        #pragma unroll
        for (int rr = 0; rr < 4; ++rr) {
            float v = rowsum[mf][rr];
            v += __shfl_xor(v, 1, 64);
            v += __shfl_xor(v, 2, 64);
            v += __shfl_xor(v, 4, 64);
            v += __shfl_xor(v, 8, 64);
            if (r15 == 0) atomicAdd(&rowsumAcc[iBase + mf * 16 + rr], v);
        }
}

// ---------------- finish: lse = log(sum)+5; mean(lse - pos) ----------------
__global__ __launch_bounds__(128)
void fin1_kernel(const float* __restrict__ rowsumAcc, const float* __restrict__ posArr,
                 float* __restrict__ blockSums) {    // [64]
    const int tid = threadIdx.x;
    const int i = blockIdx.x * 128 + tid;
    double v = (double)(logf(rowsumAcc[i]) + 5.0f - posArr[i]);
    #pragma unroll
    for (int m = 1; m < 64; m <<= 1) v += __shfl_xor(v, m, 64);
    __shared__ double red[2];
    if ((tid & 63) == 0) red[tid >> 6] = v;
    __syncthreads();
    if (tid == 0) blockSums[blockIdx.x] = (float)(red[0] + red[1]);
}

__global__ __launch_bounds__(64)
void fin2_kernel(const float* __restrict__ blockSums, float* __restrict__ out) {
    double v = (double)blockSums[threadIdx.x];
    #pragma unroll
    for (int m = 1; m < 64; m <<= 1) v += __shfl_xor(v, m, 64);
    if (threadIdx.x == 0) out[0] = (float)(v / (double)MM);
}

extern "C" void kernel_launch(void* const* d_in, const int* in_sizes, int n_in,
                              void* d_out, int out_size, void* d_ws, size_t ws_size,
                              hipStream_t stream) {
    const float* Z1 = (const float*)d_in[0];
    const float* Z2 = (const float*)d_in[1];
    float* out = (float*)d_out;
    char* ws = (char*)d_ws;
    unsigned short* Zb = (unsigned short*)ws;                         // 4 MB bf16 [8192][256]
    float* posArr = (float*)(ws + (size_t)MM * DDIM * 2);             // 32 KB
    float* rowsumAcc = (float*)(ws + (size_t)MM * DDIM * 2 + MM * 4); // 32 KB
    float* blockSums = (float*)(ws + (size_t)MM * DDIM * 2 + 2 * MM * 4); // 256 B

    nrm_kernel<<<MM / 4, 256, 0, stream>>>(Z1, Z2, Zb, rowsumAcc);
    sim_lse_kernel<<<32 * 8, 512, 0, stream>>>(Zb, rowsumAcc, posArr);
    fin1_kernel<<<64, 128, 0, stream>>>(rowsumAcc, posArr, blockSums);
    fin2_kernel<<<1, 64, 0, stream>>>(blockSums, out);
}